// Round 12
// baseline (88.669 us; speedup 1.0000x reference)
//
#include <hip/hip_runtime.h>
#include <math.h>

#ifndef M_PI
#define M_PI 3.14159265358979323846
#endif

#define NFILT   10
#define NSEC    5                   // five cascade-pair sections
#define THREADS 1024
#define CHUNK   64                  // 32 samples in VGPRs + 32 in LDS
#define REGS    32
#define LDSS    (CHUNK - REGS)
#define LTOT    (THREADS * CHUNK)   // 65536
#define NWAVE   (THREADS / 64)      // 16

#define WS_STRIDE 960               // floats per batch
#define MATS_OFF  160               // const pairs: j*32; matrices: MATS_OFF+(j*10+r)*16

typedef float v2f __attribute__((ext_vector_type(2)));
__device__ inline v2f mk2(float a, float b) { v2f r; r.x = a; r.y = b; return r; }
#define F2(a,b,c) __builtin_elementwise_fma((a),(b),(c))

// pair-step of recurrence v_t = c_t - a1 v_{t-1} - a2 v_{t-2}
// h=(0,-a1), m1=(-a1,a1^2-a2), m2=(-a2,a1*a2), pv=(v_{t-2}, v_{t-1})
__device__ inline v2f rec2(v2f C, v2f h, v2f m1, v2f m2, v2f pv) {
    const v2f Ch = F2(h, mk2(C.x, C.x), C);
    return F2(m2, mk2(pv.x, pv.x), F2(m1, mk2(pv.y, pv.y), Ch));
}
// pair FIR: c_t = f0 u_t + f1 u_{t-1} + f2 u_{t-2}, pU=(u_{t-2},u_{t-1})
__device__ inline v2f fir2(v2f U, v2f pU, v2f f0, v2f f1, v2f f2c) {
    return F2(f2c, pU, F2(f1, mk2(pU.y, U.x), f0 * U));
}

// ---------------- precompute (f64) ----------------

__device__ inline void mm4d(const double* X, const double* Y, double* Z) {
    #pragma unroll
    for (int r = 0; r < 4; ++r)
        #pragma unroll
        for (int c = 0; c < 4; ++c)
            Z[r*4+c] = X[r*4+0]*Y[c] + X[r*4+1]*Y[4+c] + X[r*4+2]*Y[8+c] + X[r*4+3]*Y[12+c];
}

__device__ inline void biquad_coefs(int k, double w0r, double qir, double gr,
                                    double* bo, double* ao) {
    const double w0 = M_PI / (1.0 + exp(-w0r));
    const double qi = exp(qir);
    const double A  = exp(gr);
    const double cw = cos(w0);
    const double al = sin(w0) * qi * 0.5;
    double B0, B1, B2, A0, A1, A2;
    if (k == 0) {
        const double Ap1 = A + 1.0, Am1 = A - 1.0, tsa = 2.0 * sqrt(A) * al;
        B0 = A * (Ap1 - Am1 * cw + tsa);
        B1 = 2.0 * A * (Am1 - Ap1 * cw);
        B2 = A * (Ap1 - Am1 * cw - tsa);
        A0 = Ap1 + Am1 * cw + tsa;
        A1 = -2.0 * (Am1 + Ap1 * cw);
        A2 = Ap1 + Am1 * cw - tsa;
    } else if (k == NFILT - 1) {
        const double Ap1 = A + 1.0, Am1 = A - 1.0, tsa = 2.0 * sqrt(A) * al;
        B0 = A * (Ap1 + Am1 * cw + tsa);
        B1 = -2.0 * A * (Am1 + Ap1 * cw);
        B2 = A * (Ap1 + Am1 * cw - tsa);
        A0 = Ap1 - Am1 * cw + tsa;
        A1 = 2.0 * (Am1 - Ap1 * cw);
        A2 = Ap1 - Am1 * cw - tsa;
    } else {
        const double aA = al * A, aiA = al / A;
        B0 = 1.0 + aA;  B1 = -2.0 * cw; B2 = 1.0 - aA;
        A0 = 1.0 + aiA; A1 = B1;        A2 = 1.0 - aiA;
    }
    const double inv = 1.0 / A0;
    bo[0] = B0 * inv; bo[1] = B1 * inv; bo[2] = B2 * inv;
    ao[0] = 1.0;      ao[1] = A1 * inv; ao[2] = A2 * inv;
}

// Per (batch, section j): biquads (2j,2j+1) in cascade form.
// Const block (12 v2f pairs) + 4x4 pair-transfer powers M^(64*2^r), r=0..9,
// stored in packed col-pair order for the v2f matvec.
__global__ void eq_precompute_kernel(const float* __restrict__ w0_in,
                                     const float* __restrict__ qinv_in,
                                     const float* __restrict__ gain_in,
                                     float* __restrict__ ws)
{
    const int b = blockIdx.x;
    const int j = threadIdx.x;
    if (j >= NSEC) return;

    double bA[3], aA[3], bB[3], aB[3];
    const int k0 = 2*j, k1 = 2*j + 1;
    biquad_coefs(k0, (double)w0_in[b*NFILT+k0], (double)qinv_in[b*NFILT+k0],
                 (double)gain_in[b*NFILT+k0], bA, aA);
    biquad_coefs(k1, (double)w0_in[b*NFILT+k1], (double)qinv_in[b*NFILT+k1],
                 (double)gain_in[b*NFILT+k1], bB, aB);

    float* wb = ws + (size_t)b * WS_STRIDE;
    float* cj = wb + j * 32;
    cj[0]=0.f;               cj[1]=(float)(-aA[1]);
    cj[2]=(float)(-aA[1]);   cj[3]=(float)(aA[1]*aA[1]-aA[2]);
    cj[4]=(float)(-aA[2]);   cj[5]=(float)(aA[1]*aA[2]);
    cj[6]=(float)bB[0];      cj[7]=(float)bB[0];
    cj[8]=(float)bB[1];      cj[9]=(float)bB[1];
    cj[10]=(float)bB[2];     cj[11]=(float)bB[2];
    cj[12]=0.f;              cj[13]=(float)(-aB[1]);
    cj[14]=(float)(-aB[1]);  cj[15]=(float)(aB[1]*aB[1]-aB[2]);
    cj[16]=(float)(-aB[2]);  cj[17]=(float)(aB[1]*aB[2]);
    cj[18]=(float)bA[0];     cj[19]=(float)bA[0];
    cj[20]=(float)bA[1];     cj[21]=(float)bA[1];
    cj[22]=(float)bA[2];     cj[23]=(float)bA[2];

    // 64-sample homogeneous pair transfer (cA = 0), state (vA1,vA2,vB1,vB2)
    double M[16], T[16];
    #pragma unroll
    for (int c = 0; c < 4; ++c) {
        double vA1 = (c==0)?1.0:0.0, vA2 = (c==1)?1.0:0.0;
        double vB1 = (c==2)?1.0:0.0, vB2 = (c==3)?1.0:0.0;
        for (int t = 0; t < CHUNK; ++t) {
            const double vA = -aA[1]*vA1 - aA[2]*vA2;
            const double cB = bB[0]*vA + bB[1]*vA1 + bB[2]*vA2;
            const double vB = cB - aB[1]*vB1 - aB[2]*vB2;
            vA2=vA1; vA1=vA; vB2=vB1; vB1=vB;
        }
        M[0*4+c]=vA1; M[1*4+c]=vA2; M[2*4+c]=vB1; M[3*4+c]=vB2;
    }
    for (int r = 0; r < 10; ++r) {
        float* mr = wb + MATS_OFF + (j*10 + r)*16;
        #pragma unroll
        for (int c = 0; c < 4; ++c) {
            mr[2*c+0]   = (float)M[0*4+c];   // (m0c, m1c) pair
            mr[2*c+1]   = (float)M[1*4+c];
            mr[8+2*c+0] = (float)M[2*4+c];   // (m2c, m3c) pair
            mr[8+2*c+1] = (float)M[3*4+c];
        }
        mm4d(M, M, T);
        #pragma unroll
        for (int e = 0; e < 16; ++e) M[e] = T[e];
    }
}

// ---------------- main kernel ----------------

__global__ void
__attribute__((amdgpu_flat_work_group_size(THREADS, THREADS)))
__attribute__((amdgpu_waves_per_eu(4, 4)))
eq_cascade_kernel(const float* __restrict__ x,
                  float* __restrict__ out,
                  const float* __restrict__ ws)
{
    __shared__ float4 sigh[LDSS/4][THREADS];   // samples 32..63 (thread-private)
    __shared__ float2 bnd[THREADS];
    __shared__ float4 waveP[2][NWAVE];

    const int tid  = threadIdx.x;
    const int lane = tid & 63;
    const int wid  = tid >> 6;
    const int b    = blockIdx.x;
    const float* __restrict__ wsb = ws + (size_t)b * WS_STRIDE;

    const float* xb = x   + (size_t)b * LTOT;
    float*       ob = out + (size_t)b * LTOT;

    float sig[REGS];

    // ---- load: first 32 -> regs, last 32 -> LDS ----
    const float4* src = reinterpret_cast<const float4*>(xb + (size_t)tid * CHUNK);
    #pragma unroll
    for (int i = 0; i < REGS/4; ++i) {
        const float4 v = src[i];
        sig[4*i+0] = v.x; sig[4*i+1] = v.y; sig[4*i+2] = v.z; sig[4*i+3] = v.w;
    }
    float4 vlast;
    #pragma unroll
    for (int i = 0; i < LDSS/4; ++i) {
        const float4 v = src[REGS/4 + i];
        sigh[i][tid] = v;
        if (i == LDSS/4 - 1) vlast = v;
    }
    bnd[tid] = make_float2(vlast.w, vlast.z);
    __syncthreads();

    float xw1, xw2;
    {
        const float2 t0 = (tid == 0) ? make_float2(0.f, 0.f) : bnd[tid - 1];
        xw1 = t0.x; xw2 = t0.y;
    }
    float i1 = 0.f, i2 = 0.f, i3 = 0.f, i4 = 0.f;

    #pragma unroll 1
    for (int j = 0; j < NSEC; ++j) {
        const v2f* cc = reinterpret_cast<const v2f*>(wsb + j*32);
        const v2f c0 = cc[0], c1 = cc[1], c2 = cc[2];     // zero-init A rec
        const v2f c3 = cc[3], c4 = cc[4], c5 = cc[5];     // FIR-B
        const v2f c6 = cc[6], c7 = cc[7], c8 = cc[8];     // zero-init B rec
        const v2f c9 = cc[9], c10 = cc[10], c11 = cc[11]; // FIR-A
        const float* mb = wsb + MATS_OFF + j*160;

        v2f pZA = mk2(0.f, 0.f), pZB = mk2(0.f, 0.f);

        if (j == 0) {
            v2f pU = mk2(xw2, xw1);
            #pragma unroll
            for (int i = 0; i < REGS/2; ++i) {
                const v2f U  = mk2(sig[2*i], sig[2*i+1]);
                const v2f CA = fir2(U, pU, c9, c10, c11);
                sig[2*i] = CA.x; sig[2*i+1] = CA.y;
                const v2f ZA  = rec2(CA, c0, c1, c2, pZA);
                const v2f CZB = fir2(ZA, pZA, c3, c4, c5);
                const v2f ZB  = rec2(CZB, c6, c7, c8, pZB);
                pU = U; pZA = ZA; pZB = ZB;
            }
            #pragma unroll
            for (int i = 0; i < LDSS/4; ++i) {
                const float4 v = sigh[i][tid];
                float4 r;
                #pragma unroll
                for (int h = 0; h < 2; ++h) {
                    const v2f U  = (h == 0) ? mk2(v.x, v.y) : mk2(v.z, v.w);
                    const v2f CA = fir2(U, pU, c9, c10, c11);
                    const v2f ZA  = rec2(CA, c0, c1, c2, pZA);
                    const v2f CZB = fir2(ZA, pZA, c3, c4, c5);
                    const v2f ZB  = rec2(CZB, c6, c7, c8, pZB);
                    if (h == 0) { r.x = CA.x; r.y = CA.y; } else { r.z = CA.x; r.w = CA.y; }
                    pU = U; pZA = ZA; pZB = ZB;
                }
                sigh[i][tid] = r;
            }
        } else {
            const v2f* pc = reinterpret_cast<const v2f*>(wsb + (j-1)*32);
            const v2f p0 = pc[0], p1 = pc[1], p2 = pc[2];
            const v2f p3 = pc[3], p4 = pc[4], p5 = pc[5];
            const v2f p6 = pc[6], p7 = pc[7], p8 = pc[8];
            v2f pVA = mk2(i2, i1), pVB = mk2(i4, i3);
            #pragma unroll
            for (int i = 0; i < REGS/2; ++i) {
                const v2f CAp = mk2(sig[2*i], sig[2*i+1]);
                const v2f VA = rec2(CAp, p0, p1, p2, pVA);   // finalize prev-A
                const v2f CB = fir2(VA, pVA, p3, p4, p5);    // prev FIR-B
                const v2f VB = rec2(CB, p6, p7, p8, pVB);    // finalize prev-B = u
                const v2f CA = fir2(VB, pVB, c9, c10, c11);  // this FIR-A
                sig[2*i] = CA.x; sig[2*i+1] = CA.y;
                const v2f ZA  = rec2(CA, c0, c1, c2, pZA);
                const v2f CZB = fir2(ZA, pZA, c3, c4, c5);
                const v2f ZB  = rec2(CZB, c6, c7, c8, pZB);
                pVA = VA; pVB = VB; pZA = ZA; pZB = ZB;
            }
            #pragma unroll
            for (int i = 0; i < LDSS/4; ++i) {
                const float4 v = sigh[i][tid];
                float4 r;
                #pragma unroll
                for (int h = 0; h < 2; ++h) {
                    const v2f CAp = (h == 0) ? mk2(v.x, v.y) : mk2(v.z, v.w);
                    const v2f VA = rec2(CAp, p0, p1, p2, pVA);
                    const v2f CB = fir2(VA, pVA, p3, p4, p5);
                    const v2f VB = rec2(CB, p6, p7, p8, pVB);
                    const v2f CA = fir2(VB, pVB, c9, c10, c11);
                    const v2f ZA  = rec2(CA, c0, c1, c2, pZA);
                    const v2f CZB = fir2(ZA, pZA, c3, c4, c5);
                    const v2f ZB  = rec2(CZB, c6, c7, c8, pZB);
                    if (h == 0) { r.x = CA.x; r.y = CA.y; } else { r.z = CA.x; r.w = CA.y; }
                    pVA = VA; pVB = VB; pZA = ZA; pZB = ZB;
                }
                sigh[i][tid] = r;
            }
        }

        // ---- in-wave inclusive affine scan of s=(zA1,zA2,zB1,zB2) ----
        v2f S01 = mk2(pZA.y, pZA.x);
        v2f S23 = mk2(pZB.y, pZB.x);
        #pragma unroll
        for (int r = 0; r < 6; ++r) {
            const int d = 1 << r;
            const v2f* mp = reinterpret_cast<const v2f*>(mb + r*16);
            float t0 = __shfl_up(S01.x, d, 64), t1 = __shfl_up(S01.y, d, 64);
            float t2 = __shfl_up(S23.x, d, 64), t3 = __shfl_up(S23.y, d, 64);
            const bool act = (lane >= d);
            t0 = act ? t0 : 0.f; t1 = act ? t1 : 0.f;
            t2 = act ? t2 : 0.f; t3 = act ? t3 : 0.f;
            S01 = F2(mp[0], mk2(t0,t0), S01); S01 = F2(mp[1], mk2(t1,t1), S01);
            S01 = F2(mp[2], mk2(t2,t2), S01); S01 = F2(mp[3], mk2(t3,t3), S01);
            S23 = F2(mp[4], mk2(t0,t0), S23); S23 = F2(mp[5], mk2(t1,t1), S23);
            S23 = F2(mp[6], mk2(t2,t2), S23); S23 = F2(mp[7], mk2(t3,t3), S23);
        }
        const int buf = j & 1;
        if (lane == 63) waveP[buf][wid] = make_float4(S01.x, S01.y, S23.x, S23.y);
        __syncthreads();

        // ---- cross-wave: 4-level KS over 16 wave totals (lane space) ----
        const float4 Pv = waveP[buf][lane & 15];
        v2f T01 = mk2(Pv.x, Pv.y), T23 = mk2(Pv.z, Pv.w);
        #pragma unroll
        for (int l = 0; l < 4; ++l) {
            const int d = 1 << l;
            const v2f* mp = reinterpret_cast<const v2f*>(mb + (6+l)*16);
            float t0 = __shfl_up(T01.x, d, 64), t1 = __shfl_up(T01.y, d, 64);
            float t2 = __shfl_up(T23.x, d, 64), t3 = __shfl_up(T23.y, d, 64);
            const bool act = (lane >= d);
            t0 = act ? t0 : 0.f; t1 = act ? t1 : 0.f;
            t2 = act ? t2 : 0.f; t3 = act ? t3 : 0.f;
            T01 = F2(mp[0], mk2(t0,t0), T01); T01 = F2(mp[1], mk2(t1,t1), T01);
            T01 = F2(mp[2], mk2(t2,t2), T01); T01 = F2(mp[3], mk2(t3,t3), T01);
            T23 = F2(mp[4], mk2(t0,t0), T23); T23 = F2(mp[5], mk2(t1,t1), T23);
            T23 = F2(mp[6], mk2(t2,t2), T23); T23 = F2(mp[7], mk2(t3,t3), T23);
        }
        // wave-incoming state V = T_{wid-1} (zero at signal start)
        float v0 = __shfl(T01.x, wid - 1, 64), v1 = __shfl(T01.y, wid - 1, 64);
        float v2 = __shfl(T23.x, wid - 1, 64), v3 = __shfl(T23.y, wid - 1, 64);
        if (wid == 0) { v0 = v1 = v2 = v3 = 0.f; }
        v2f V01 = mk2(v0, v1), V23 = mk2(v2, v3);
        #pragma unroll
        for (int r = 0; r < 6; ++r) {      // apply M^(64*lane)
            const v2f* mp = reinterpret_cast<const v2f*>(mb + r*16);
            v2f N01 = mp[0] * mk2(V01.x, V01.x);
            N01 = F2(mp[1], mk2(V01.y, V01.y), N01);
            N01 = F2(mp[2], mk2(V23.x, V23.x), N01);
            N01 = F2(mp[3], mk2(V23.y, V23.y), N01);
            v2f N23 = mp[4] * mk2(V01.x, V01.x);
            N23 = F2(mp[5], mk2(V01.y, V01.y), N23);
            N23 = F2(mp[6], mk2(V23.x, V23.x), N23);
            N23 = F2(mp[7], mk2(V23.y, V23.y), N23);
            const bool bit = (lane >> r) & 1;
            V01 = bit ? N01 : V01;
            V23 = bit ? N23 : V23;
        }
        // + exclusive in-wave particular prefix
        float e0 = __shfl_up(S01.x, 1, 64), e1 = __shfl_up(S01.y, 1, 64);
        float e2 = __shfl_up(S23.x, 1, 64), e3 = __shfl_up(S23.y, 1, 64);
        if (lane == 0) { e0 = e1 = e2 = e3 = 0.f; }
        i1 = V01.x + e0; i2 = V01.y + e1; i3 = V23.x + e2; i4 = V23.y + e3;
    }

    // ---- tail: finalize section 4 + store ----
    {
        const v2f* pc = reinterpret_cast<const v2f*>(wsb + (NSEC-1)*32);
        const v2f p0 = pc[0], p1 = pc[1], p2 = pc[2];
        const v2f p3 = pc[3], p4 = pc[4], p5 = pc[5];
        const v2f p6 = pc[6], p7 = pc[7], p8 = pc[8];
        v2f pVA = mk2(i2, i1), pVB = mk2(i4, i3);
        float4* dst = reinterpret_cast<float4*>(ob + (size_t)tid * CHUNK);
        #pragma unroll
        for (int i = 0; i < REGS/4; ++i) {
            float4 o;
            #pragma unroll
            for (int h = 0; h < 2; ++h) {
                const v2f CAp = (h == 0) ? mk2(sig[4*i], sig[4*i+1]) : mk2(sig[4*i+2], sig[4*i+3]);
                const v2f VA = rec2(CAp, p0, p1, p2, pVA);
                const v2f CB = fir2(VA, pVA, p3, p4, p5);
                const v2f VB = rec2(CB, p6, p7, p8, pVB);
                if (h == 0) { o.x = VB.x; o.y = VB.y; } else { o.z = VB.x; o.w = VB.y; }
                pVA = VA; pVB = VB;
            }
            dst[i] = o;
        }
        #pragma unroll
        for (int i = 0; i < LDSS/4; ++i) {
            const float4 v = sigh[i][tid];
            float4 o;
            #pragma unroll
            for (int h = 0; h < 2; ++h) {
                const v2f CAp = (h == 0) ? mk2(v.x, v.y) : mk2(v.z, v.w);
                const v2f VA = rec2(CAp, p0, p1, p2, pVA);
                const v2f CB = fir2(VA, pVA, p3, p4, p5);
                const v2f VB = rec2(CB, p6, p7, p8, pVB);
                if (h == 0) { o.x = VB.x; o.y = VB.y; } else { o.z = VB.x; o.w = VB.y; }
                pVA = VA; pVB = VB;
            }
            dst[REGS/4 + i] = o;
        }
    }
}

extern "C" void kernel_launch(void* const* d_in, const int* in_sizes, int n_in,
                              void* d_out, int out_size, void* d_ws, size_t ws_size,
                              hipStream_t stream) {
    const float* x    = (const float*)d_in[0];
    const float* w0   = (const float*)d_in[1];
    const float* qinv = (const float*)d_in[2];
    const float* gain = (const float*)d_in[3];
    float* out = (float*)d_out;
    float* ws  = (float*)d_ws;   // 256 * 960 * 4 B = 983 KiB

    const int B = in_sizes[1] / NFILT;   // 256 batches
    eq_precompute_kernel<<<B, 64, 0, stream>>>(w0, qinv, gain, ws);
    eq_cascade_kernel<<<B, THREADS, 0, stream>>>(x, out, ws);
}

// Round 13
// 82.578 us; speedup vs baseline: 1.0738x; 1.0738x over previous
//
#include <hip/hip_runtime.h>
#include <math.h>

#ifndef M_PI
#define M_PI 3.14159265358979323846
#endif

#define NFILT   10
#define THREADS 1024
#define CHUNK   64                  // 40 samples in VGPRs + 24 in LDS
#define REGS    40
#define LDSS    (CHUNK - REGS)      // 24
#define LTOT    (THREADS * CHUNK)   // 65536
#define NWAVE   (THREADS / 64)      // 16

#define WS_STRIDE 576               // floats per batch
#define MATS_OFF  96                // coefs: j*8; matrices: (j*10+r)*4

typedef float v2f __attribute__((ext_vector_type(2)));
__device__ inline v2f mk2(float a, float b) { v2f r; r.x = a; r.y = b; return r; }
#define F2(a,b,c) __builtin_elementwise_fma((a),(b),(c))

// ---------------- precompute (f64) ----------------

__device__ inline void biquad_coefs(int k, double w0r, double qir, double gr,
                                    double* bo, double* ao) {
    const double w0 = M_PI / (1.0 + exp(-w0r));
    const double qi = exp(qir);
    const double A  = exp(gr);
    const double cw = cos(w0);
    const double al = sin(w0) * qi * 0.5;
    double B0, B1, B2, A0, A1, A2;
    if (k == 0) {
        const double Ap1 = A + 1.0, Am1 = A - 1.0, tsa = 2.0 * sqrt(A) * al;
        B0 = A * (Ap1 - Am1 * cw + tsa);
        B1 = 2.0 * A * (Am1 - Ap1 * cw);
        B2 = A * (Ap1 - Am1 * cw - tsa);
        A0 = Ap1 + Am1 * cw + tsa;
        A1 = -2.0 * (Am1 + Ap1 * cw);
        A2 = Ap1 + Am1 * cw - tsa;
    } else if (k == NFILT - 1) {
        const double Ap1 = A + 1.0, Am1 = A - 1.0, tsa = 2.0 * sqrt(A) * al;
        B0 = A * (Ap1 + Am1 * cw + tsa);
        B1 = -2.0 * A * (Am1 + Ap1 * cw);
        B2 = A * (Ap1 + Am1 * cw - tsa);
        A0 = Ap1 - Am1 * cw + tsa;
        A1 = 2.0 * (Am1 - Ap1 * cw);
        A2 = Ap1 - Am1 * cw - tsa;
    } else {
        const double aA = al * A, aiA = al / A;
        B0 = 1.0 + aA;  B1 = -2.0 * cw; B2 = 1.0 - aA;
        A0 = 1.0 + aiA; A1 = B1;        A2 = 1.0 - aiA;
    }
    const double inv = 1.0 / A0;
    bo[0] = B0 * inv; bo[1] = B1 * inv; bo[2] = B2 * inv;
    ao[0] = 1.0;      ao[1] = A1 * inv; ao[2] = A2 * inv;
}

// coefs per filter j: [b0,b1,b2,a1,a2, qa1=a1^2-a2, qa2=a1*a2, 0]
// matrices: C^(64*2^r), r=0..9, row-major (m0,m1,m2,m3)
__global__ void eq_precompute_kernel(const float* __restrict__ w0_in,
                                     const float* __restrict__ qinv_in,
                                     const float* __restrict__ gain_in,
                                     float* __restrict__ ws)
{
    const int b = blockIdx.x;
    const int j = threadIdx.x;
    if (j >= NFILT) return;

    double bo[3], ao[3];
    biquad_coefs(j, (double)w0_in[b*NFILT+j], (double)qinv_in[b*NFILT+j],
                 (double)gain_in[b*NFILT+j], bo, ao);

    float* wb = ws + (size_t)b * WS_STRIDE;
    float* cj = wb + j * 8;
    cj[0] = (float)bo[0]; cj[1] = (float)bo[1]; cj[2] = (float)bo[2];
    cj[3] = (float)ao[1]; cj[4] = (float)ao[2];
    cj[5] = (float)(ao[1]*ao[1] - ao[2]);   // qa1
    cj[6] = (float)(ao[1]*ao[2]);           // qa2

    double m0 = -ao[1], m1 = -ao[2], m2 = 1.0, m3 = 0.0;   // C
    #pragma unroll
    for (int i = 0; i < 6; ++i) {                          // -> C^64
        const double n0 = m0*m0 + m1*m2, n1 = m0*m1 + m1*m3;
        const double n2 = m2*m0 + m3*m2, n3 = m2*m1 + m3*m3;
        m0 = n0; m1 = n1; m2 = n2; m3 = n3;
    }
    for (int r = 0; r < 10; ++r) {                         // C^(64*2^r)
        float* mr = wb + MATS_OFF + (j*10 + r)*4;
        mr[0] = (float)m0; mr[1] = (float)m1; mr[2] = (float)m2; mr[3] = (float)m3;
        const double n0 = m0*m0 + m1*m2, n1 = m0*m1 + m1*m3;
        const double n2 = m2*m0 + m3*m2, n3 = m2*m1 + m3*m3;
        m0 = n0; m1 = n1; m2 = n2; m3 = n3;
    }
}

// ---------------- main kernel ----------------

__global__ void
__attribute__((amdgpu_flat_work_group_size(THREADS, THREADS)))
__attribute__((amdgpu_waves_per_eu(4, 4)))
eq_cascade_kernel(const float* __restrict__ x,
                  float* __restrict__ out,
                  const float* __restrict__ ws)
{
    __shared__ float4 sigh[LDSS/4][THREADS];   // samples 40..63 (thread-private)
    __shared__ float2 bnd[THREADS];
    __shared__ float2 waveP[2][NWAVE];

    const int tid  = threadIdx.x;
    const int lane = tid & 63;
    const int wid  = tid >> 6;
    const int b    = blockIdx.x;
    const float* __restrict__ wsb = ws + (size_t)b * WS_STRIDE;

    const float* xb = x   + (size_t)b * LTOT;
    float*       ob = out + (size_t)b * LTOT;

    float sig[REGS];

    // ---- load 64 samples: first 40 -> regs, last 24 -> LDS ----
    const float4* src = reinterpret_cast<const float4*>(xb + (size_t)tid * CHUNK);
    #pragma unroll
    for (int i = 0; i < REGS/4; ++i) {
        const float4 v = src[i];
        sig[4*i+0] = v.x; sig[4*i+1] = v.y; sig[4*i+2] = v.z; sig[4*i+3] = v.w;
    }
    float4 vlast;
    #pragma unroll
    for (int i = 0; i < LDSS/4; ++i) {
        const float4 v = src[REGS/4 + i];
        sigh[i][tid] = v;
        if (i == LDSS/4 - 1) vlast = v;
    }
    bnd[tid] = make_float2(vlast.w, vlast.z);
    __syncthreads();

    float xw1, xw2;
    {
        const float2 t0 = (tid == 0) ? make_float2(0.f, 0.f) : bnd[tid - 1];
        xw1 = t0.x; xw2 = t0.y;
    }
    float i1 = 0.f, i2 = 0.f;
    v2f PA0p = mk2(0.f, 0.f), PA1p = mk2(0.f, 0.f), PA2p = mk2(0.f, 0.f);

    #pragma unroll 1
    for (int j = 0; j < NFILT; ++j) {
        const float* cj = wsb + j*8;
        const float b0 = cj[0], b1c = cj[1], b2 = cj[2];
        const float a1 = cj[3], a2 = cj[4], qa1 = cj[5], qa2 = cj[6];
        const v2f B0v = mk2(b0, b0), B1v = mk2(b1c, b1c), B2v = mk2(b2, b2);
        const v2f A0v = mk2(0.f, -a1), A1v = mk2(-a1, qa1), A2v = mk2(-a2, qa2);
        const float* mb = wsb + MATS_OFF + j*40;

        // ---- fused packed: finalize(j-1) + FIR(j) + zero-init(j), pair-stepped ----
        v2f Zp = mk2(0.f, 0.f);
        v2f Up;
        if (j == 0) {
            Up = mk2(xw2, xw1);       // (u_{-2}, u_{-1}) = raw x history
            #pragma unroll
            for (int i = 0; i < REGS/2; ++i) {
                const v2f U  = mk2(sig[2*i], sig[2*i+1]);      // u = raw input
                const v2f M1 = mk2(Up.y, U.x);
                const v2f C  = F2(B2v, Up, F2(B1v, M1, B0v*U));
                const v2f Ch = F2(A0v, mk2(C.x, C.x), C);
                const v2f Z  = F2(A2v, mk2(Zp.x, Zp.x), F2(A1v, mk2(Zp.y, Zp.y), Ch));
                sig[2*i] = C.x; sig[2*i+1] = C.y;
                Up = U; Zp = Z;
            }
            #pragma unroll
            for (int i = 0; i < LDSS/4; ++i) {
                const float4 v = sigh[i][tid];
                float4 r;
                #pragma unroll
                for (int h = 0; h < 2; ++h) {
                    const v2f U  = (h == 0) ? mk2(v.x, v.y) : mk2(v.z, v.w);
                    const v2f M1 = mk2(Up.y, U.x);
                    const v2f C  = F2(B2v, Up, F2(B1v, M1, B0v*U));
                    const v2f Ch = F2(A0v, mk2(C.x, C.x), C);
                    const v2f Z  = F2(A2v, mk2(Zp.x, Zp.x), F2(A1v, mk2(Zp.y, Zp.y), Ch));
                    if (h == 0) { r.x = C.x; r.y = C.y; } else { r.z = C.x; r.w = C.y; }
                    Up = U; Zp = Z;
                }
                sigh[i][tid] = r;
            }
        } else {
            Up = mk2(i2, i1);         // (u_{-2}, u_{-1}) = true prev-filter output state
            #pragma unroll
            for (int i = 0; i < REGS/2; ++i) {
                const v2f S  = mk2(sig[2*i], sig[2*i+1]);
                const v2f Sh = F2(PA0p, mk2(S.x, S.x), S);
                const v2f U  = F2(PA2p, mk2(Up.x, Up.x), F2(PA1p, mk2(Up.y, Up.y), Sh));
                const v2f M1 = mk2(Up.y, U.x);
                const v2f C  = F2(B2v, Up, F2(B1v, M1, B0v*U));
                const v2f Ch = F2(A0v, mk2(C.x, C.x), C);
                const v2f Z  = F2(A2v, mk2(Zp.x, Zp.x), F2(A1v, mk2(Zp.y, Zp.y), Ch));
                sig[2*i] = C.x; sig[2*i+1] = C.y;
                Up = U; Zp = Z;
            }
            #pragma unroll
            for (int i = 0; i < LDSS/4; ++i) {
                const float4 v = sigh[i][tid];
                float4 r;
                #pragma unroll
                for (int h = 0; h < 2; ++h) {
                    const v2f S  = (h == 0) ? mk2(v.x, v.y) : mk2(v.z, v.w);
                    const v2f Sh = F2(PA0p, mk2(S.x, S.x), S);
                    const v2f U  = F2(PA2p, mk2(Up.x, Up.x), F2(PA1p, mk2(Up.y, Up.y), Sh));
                    const v2f M1 = mk2(Up.y, U.x);
                    const v2f C  = F2(B2v, Up, F2(B1v, M1, B0v*U));
                    const v2f Ch = F2(A0v, mk2(C.x, C.x), C);
                    const v2f Z  = F2(A2v, mk2(Zp.x, Zp.x), F2(A1v, mk2(Zp.y, Zp.y), Ch));
                    if (h == 0) { r.x = C.x; r.y = C.y; } else { r.z = C.x; r.w = C.y; }
                    Up = U; Zp = Z;
                }
                sigh[i][tid] = r;
            }
        }

        // ---- in-wave inclusive affine scan of (z_newest, z_second) ----
        float Sa = Zp.y, Sb = Zp.x;
        #pragma unroll
        for (int r = 0; r < 6; ++r) {
            const int d = 1 << r;
            const float4 M = *reinterpret_cast<const float4*>(mb + r*4);
            float ta = __shfl_up(Sa, d, 64);
            float tb = __shfl_up(Sb, d, 64);
            const bool act = (lane >= d);
            ta = act ? ta : 0.f;
            tb = act ? tb : 0.f;
            Sa = Sa + M.x * ta + M.y * tb;
            Sb = Sb + M.z * ta + M.w * tb;
        }
        const int buf = j & 1;
        if (lane == 63) waveP[buf][wid] = make_float2(Sa, Sb);
        __syncthreads();

        // ---- cross-wave: 4-level KS over 16 wave totals ----
        const float2 Pv = waveP[buf][lane & 15];
        float Tx = Pv.x, Ty = Pv.y;
        #pragma unroll
        for (int l = 0; l < 4; ++l) {
            const int d = 1 << l;
            const float4 M = *reinterpret_cast<const float4*>(mb + (6+l)*4);
            float tx = __shfl_up(Tx, d, 64);
            float ty = __shfl_up(Ty, d, 64);
            const bool act = (lane >= d);
            tx = act ? tx : 0.f;
            ty = act ? ty : 0.f;
            Tx = Tx + M.x * tx + M.y * ty;
            Ty = Ty + M.z * tx + M.w * ty;
        }
        float Vx = __shfl(Tx, wid - 1, 64);
        float Vy = __shfl(Ty, wid - 1, 64);
        if (wid == 0) { Vx = 0.f; Vy = 0.f; }
        #pragma unroll
        for (int r = 0; r < 6; ++r) {      // apply C^(64*lane)
            const float4 M = *reinterpret_cast<const float4*>(mb + r*4);
            const bool bit = (lane >> r) & 1;
            const float nx = M.x * Vx + M.y * Vy;
            const float ny = M.z * Vx + M.w * Vy;
            Vx = bit ? nx : Vx;
            Vy = bit ? ny : Vy;
        }
        {
            float Ea = __shfl_up(Sa, 1, 64);
            float Eb = __shfl_up(Sb, 1, 64);
            const bool l0 = (lane == 0);
            i1 = Vx + (l0 ? 0.f : Ea);
            i2 = Vy + (l0 ? 0.f : Eb);
        }
        PA0p = A0v; PA1p = A1v; PA2p = A2v;
    }

    // ---- tail: packed finalize of filter 9 + store ----
    {
        v2f Up = mk2(i2, i1);
        float4* dst = reinterpret_cast<float4*>(ob + (size_t)tid * CHUNK);
        #pragma unroll
        for (int i = 0; i < REGS/4; ++i) {
            float4 o;
            #pragma unroll
            for (int h = 0; h < 2; ++h) {
                const v2f S  = (h == 0) ? mk2(sig[4*i], sig[4*i+1]) : mk2(sig[4*i+2], sig[4*i+3]);
                const v2f Sh = F2(PA0p, mk2(S.x, S.x), S);
                const v2f U  = F2(PA2p, mk2(Up.x, Up.x), F2(PA1p, mk2(Up.y, Up.y), Sh));
                if (h == 0) { o.x = U.x; o.y = U.y; } else { o.z = U.x; o.w = U.y; }
                Up = U;
            }
            dst[i] = o;
        }
        #pragma unroll
        for (int i = 0; i < LDSS/4; ++i) {
            const float4 v = sigh[i][tid];
            float4 o;
            #pragma unroll
            for (int h = 0; h < 2; ++h) {
                const v2f S  = (h == 0) ? mk2(v.x, v.y) : mk2(v.z, v.w);
                const v2f Sh = F2(PA0p, mk2(S.x, S.x), S);
                const v2f U  = F2(PA2p, mk2(Up.x, Up.x), F2(PA1p, mk2(Up.y, Up.y), Sh));
                if (h == 0) { o.x = U.x; o.y = U.y; } else { o.z = U.x; o.w = U.y; }
                Up = U;
            }
            dst[REGS/4 + i] = o;
        }
    }
}

extern "C" void kernel_launch(void* const* d_in, const int* in_sizes, int n_in,
                              void* d_out, int out_size, void* d_ws, size_t ws_size,
                              hipStream_t stream) {
    const float* x    = (const float*)d_in[0];
    const float* w0   = (const float*)d_in[1];
    const float* qinv = (const float*)d_in[2];
    const float* gain = (const float*)d_in[3];
    float* out = (float*)d_out;
    float* ws  = (float*)d_ws;   // 256 * 576 * 4 B = 576 KiB

    const int B = in_sizes[1] / NFILT;   // 256 batches
    eq_precompute_kernel<<<B, 64, 0, stream>>>(w0, qinv, gain, ws);
    eq_cascade_kernel<<<B, THREADS, 0, stream>>>(x, out, ws);
}